// Round 4
// baseline (1553.074 us; speedup 1.0000x reference)
//
#include <hip/hip_runtime.h>
#include <hip/hip_bf16.h>

typedef unsigned short u16;
typedef unsigned int u32;
typedef __attribute__((ext_vector_type(8))) short short8;
typedef __attribute__((ext_vector_type(4))) float f32x4;

#define DEVI static __device__ __forceinline__

DEVI u16 f2b(float f) {
    union { float f; unsigned v; } x; x.f = f;
    unsigned r = x.v + 0x7fffu + ((x.v >> 16) & 1u);
    return (u16)(r >> 16);
}
DEVI float b2f(u16 u) { union { unsigned v; float f; } x; x.v = ((unsigned)u) << 16; return x.f; }

#define MFMA(a, b, c) __builtin_amdgcn_mfma_f32_16x16x32_bf16((a), (b), (c), 0, 0, 0)

// XOR-swizzle for [64][128] bf16 A-tiles: permute 16B granules within a row
// by row&7 so column-strided b128 reads spread over all 32 banks.
DEVI int swz(int row, int col) {
    return row * 128 + ((((col >> 3) ^ (row & 7))) << 3) + (col & 7);
}

// ws layout:
//   [0 .. RW_END) bf16 elems           : repacked MFMA B-fragment weights
//   then f32 region (FT_* float offs)  : transposed f32 weights for VALU phases
//   then qpre f32 [2][4][128]
#define RW_PEW     0
#define RW_I1M0_WK 16384
#define RW_I1M0_WV 49152
#define RW_I1M1_WQ 81920
#define RW_I1M1_WO 114688
#define RW_I2M0_WK 131072
#define RW_I2M0_WV 147456
#define RW_I2M1_WQ 163840
#define RW_I2M1_WO 180224
#define RW_DEC_WK  196608
#define RW_DEC_WV  212992
#define RW_END     229376   // bf16 elems

// f32 transposed weights, offsets in floats from ft base
#define FT_I1M0_WO 0
#define FT_I2M0_WO 16384
#define FT_I1M1_WK 32768
#define FT_I1M1_WV 49152
#define FT_I2M1_WK 65536
#define FT_I2M1_WV 81920
#define FT_DEC_WO  98304
#define FT_DEC_WQ  114688
#define FT_OUT_W   147456
#define FT_END     180224

#define PA 128   // logical pitch of [64][128] tiles (swizzled addressing via swz())
#define PT 64    // pitch of transposed-K buffers [128][64] (unswizzled)
#define SCALE 0.08838834764831845f  // 1/sqrt(128)

struct Params {
    const float* in[49];   // ALL reference inputs are float32
    const u16* wrep;       // repacked bf16 weight fragments
    const float* ft;       // transposed f32 weights
    const float* qpre;     // [2][4][128] fp32 (precomputed I@wq+bq for i1m0 / i2m0)
    float* out;            // float32 output
};

struct RepArgs {
    const float* src[11];
    const float* tsrc[9];
    u16* dst;
    float* fdst;
    float* qpre;
    const float* I1; const float* wq1; const float* bq1;
    const float* I2; const float* wq2; const float* bq2;
};

// Repack f32 weights [K][N] row-major -> bf16 MFMA B fragments (t < 28672),
// transposed f32 copies wT[n*K+k] = w[k*N+n] (28672 <= t < 51200),
// batch-independent Qp for the two ISAB m0 blocks (t >= 51200).
__global__ void repack_kernel(RepArgs a) {
    const int offs[11] = {RW_PEW, RW_I1M0_WK, RW_I1M0_WV, RW_I1M1_WQ, RW_I1M1_WO,
                          RW_I2M0_WK, RW_I2M0_WV, RW_I2M1_WQ, RW_I2M1_WO, RW_DEC_WK, RW_DEC_WV};
    const int Ks[11] = {64, 256, 256, 256, 128, 128, 128, 128, 128, 128, 128};
    const int Ns[11] = {256, 128, 128, 128, 128, 128, 128, 128, 128, 128, 128};
    int t = blockIdx.x * 256 + threadIdx.x;
    if (t < 28672) {
        int m = 0, u = t;
        for (m = 0; m < 11; ++m) {
            int un = (Ks[m] * Ns[m]) >> 3;
            if (u < un) break;
            u -= un;
        }
        int l = u & 63, f = u >> 6;
        int ksteps = Ks[m] >> 5;
        int nt = f / ksteps, ks = f - nt * ksteps;
        int N = Ns[m];
        const float* s = a.src[m] + (ks * 32 + (l >> 4) * 8) * N + nt * 16 + (l & 15);
        u16* d = a.dst + offs[m] + ((f * 64 + l) << 3);
        short8 v;
        #pragma unroll
        for (int j = 0; j < 8; ++j) v[j] = (short)f2b(s[j * N]);
        *(short8*)d = v;
    } else if (t < 51200) {
        // transposed f32 repack: each thread writes 8 contiguous k at one n
        const int TK[9] = {128, 128, 128, 128, 128, 128, 128, 256, 128};
        const int TN[9] = {128, 128, 128, 128, 128, 128, 128, 128, 256};
        const int TOFF[9] = {FT_I1M0_WO, FT_I2M0_WO, FT_I1M1_WK, FT_I1M1_WV,
                             FT_I2M1_WK, FT_I2M1_WV, FT_DEC_WO, FT_DEC_WQ, FT_OUT_W};
        int u = t - 28672;
        int m = 0;
        for (m = 0; m < 9; ++m) {
            int un = (TK[m] * TN[m]) >> 3;
            if (u < un) break;
            u -= un;
        }
        int K = TK[m], N = TN[m];
        int kc = K >> 3;
        int n = u / kc, k0 = (u - n * kc) << 3;
        const float* s = a.tsrc[m] + k0 * N + n;
        float* d = a.fdst + TOFF[m] + n * K + k0;
        f32x4 v0, v1;
        #pragma unroll
        for (int j = 0; j < 4; ++j) v0[j] = s[j * N];
        #pragma unroll
        for (int j = 0; j < 4; ++j) v1[j] = s[(4 + j) * N];
        *(f32x4*)d = v0;
        *(f32x4*)(d + 4) = v1;
    } else {
        int q_t = t - 51200;             // 0..1023
        int which = q_t >> 9, q = (q_t >> 7) & 3, n = q_t & 127;
        const float* I  = which ? a.I2  : a.I1;
        const float* wq = which ? a.wq2 : a.wq1;
        const float* bq = which ? a.bq2 : a.bq1;
        float acc = bq[n];
        for (int k = 0; k < 128; ++k) acc += I[q * 128 + k] * wq[k * 128 + n];
        a.qpre[q_t] = acc;
    }
}

// [64,128] = A(lds, swizzled [64][128] bf16) @ Brep(K=128, repacked bf16) + bias(f32)
// MODE 0: out swizzled [64][128]   MODE 1: transposed out[col*PT+row] (unswizzled)
// MODE 2: out = A + relu(D+bias)  (residual = A), out swizzled
template <int MODE>
DEVI void gemm128(const u16* A, const u16* __restrict__ Brep,
                  const float* __restrict__ bias, u16* out, int tid) {
    int l = tid & 63, w = tid >> 6;
    int lr = l & 15, lq = l >> 4;
    int Mt = w & 3, Ntb = (w >> 2) * 4;
    f32x4 z = {0.f, 0.f, 0.f, 0.f};
    f32x4 acc[4];
    #pragma unroll
    for (int i = 0; i < 4; ++i) acc[i] = z;
    int arow = Mt * 16 + lr;
    #pragma unroll
    for (int ks = 0; ks < 4; ++ks) {
        short8 af = *(const short8*)(A + swz(arow, ks * 32 + lq * 8));
        #pragma unroll
        for (int i = 0; i < 4; ++i) {
            int nt = Ntb + i;
            short8 bfr = *(const short8*)(Brep + (((nt << 2) + ks) * 64 + l) * 8);
            acc[i] = MFMA(af, bfr, acc[i]);
        }
    }
    #pragma unroll
    for (int i = 0; i < 4; ++i) {
        int col = (Ntb + i) * 16 + lr;
        float bv = bias[col];
        #pragma unroll
        for (int r = 0; r < 4; ++r) {
            int row = Mt * 16 + lq * 4 + r;
            float v = acc[i][r] + bv;
            if (MODE == 2) v = b2f(A[swz(row, col)]) + fmaxf(v, 0.f);
            if (MODE == 1) out[col * PT + row] = f2b(v);
            else           out[swz(row, col)] = f2b(v);
        }
    }
}

// ISAB m0 attention: Sq=4 (qpre fp32), Sk=64. KT=[128][PT] bf16 (unswizzled),
// V = swizzled [64][128] bf16.
// scr aliases KT's storage as float (KT dead after the score phase):
//   scr[0..512)   = O^T  [n][q]
//   scr[512..1024)= H'^T [n][q]   (survives until att_m1's K2/V2 phase)
DEVI void att_m0(const float* __restrict__ qpre, const float* __restrict__ woT,
                 const float* __restrict__ bo, const u16* KT, const u16* V,
                 float* scr, float* sS, int tid) {
    #pragma unroll
    for (int ii = 0; ii < 2; ++ii) {         // 1024 scores: s[h][q][k]
        int idx = tid + ii * 512;
        int h = idx >> 8, q = (idx >> 6) & 3, k = idx & 63;
        const float* qp = qpre + q * 128 + h * 32;
        const u16* kp = KT + (h * 32) * PT + k;
        float s = 0.f;
        #pragma unroll
        for (int d8 = 0; d8 < 8; ++d8) {
            f32x4 q4 = *(const f32x4*)(qp + d8 * 4);
            #pragma unroll
            for (int j = 0; j < 4; ++j) s += q4[j] * b2f(kp[(d8 * 4 + j) * PT]);
        }
        sS[(h * 4 + q) * 64 + k] = s * SCALE;
    }
    __syncthreads();
    {   // softmax over k=64 for 16 rows
        int w = tid >> 6, l = tid & 63;
        int row = w * 2 + (l >> 5);
        int j = (l & 31) * 2;
        float e0 = sS[row * 64 + j], e1 = sS[row * 64 + j + 1];
        float m = fmaxf(e0, e1);
        #pragma unroll
        for (int off = 1; off < 32; off <<= 1) m = fmaxf(m, __shfl_xor(m, off));
        e0 = __expf(e0 - m); e1 = __expf(e1 - m);
        float su = e0 + e1;
        #pragma unroll
        for (int off = 1; off < 32; off <<= 1) su += __shfl_xor(su, off);
        float inv = 1.f / su;
        sS[row * 64 + j] = e0 * inv;
        sS[row * 64 + j + 1] = e1 * inv;
    }
    __syncthreads();
    {   // O^T = qpre + A*V  -> scr[n*4+q]  (KT dead now; conflict-free writes)
        int q = tid & 3, n = tid >> 2, h = n >> 5;
        float o = qpre[q * 128 + n];
        const float* ar = sS + (h * 4 + q) * 64;
        #pragma unroll 8
        for (int k8 = 0; k8 < 16; ++k8) {
            f32x4 a4 = *(const f32x4*)(ar + k8 * 4);
            #pragma unroll
            for (int j = 0; j < 4; ++j) o += a4[j] * b2f(V[swz(k8 * 4 + j, n)]);
        }
        scr[n * 4 + q] = o;
    }
    __syncthreads();
    if (tid < 256) {   // O@wo partials (k split 2), transposed f32 weights
        int n = tid & 127, c = tid >> 7;
        const float* wp = woT + n * 128 + c * 64;
        f32x4 acc = {0.f, 0.f, 0.f, 0.f};
        #pragma unroll 4
        for (int k4 = 0; k4 < 16; ++k4) {
            f32x4 w4 = *(const f32x4*)(wp + k4 * 4);
            #pragma unroll
            for (int j = 0; j < 4; ++j) {
                f32x4 o4 = *(const f32x4*)(scr + (c * 64 + k4 * 4 + j) * 4);
                acc[0] += o4[0] * w4[j]; acc[1] += o4[1] * w4[j];
                acc[2] += o4[2] * w4[j]; acc[3] += o4[3] * w4[j];
            }
        }
        *(f32x4*)(sS + c * 512 + n * 4) = acc;
    }
    __syncthreads();
    {   // H'^T = O + relu(O@wo + bo) -> scr[512 + n*4 + q]
        int q = tid & 3, n = tid >> 2;
        float val = sS[n * 4 + q] + sS[512 + n * 4 + q] + bo[n];
        scr[512 + n * 4 + q] = scr[n * 4 + q] + fmaxf(val, 0.f);
    }
    __syncthreads();
}

// ISAB m1 attention: Sq=64 (QpO = swizzled Qp tile, bf16), Sk=4.
// HT = H'^T [128][4] f32 (R0f+512). kv = raw f32 scratch (overlay on a dead tile):
// K2 = kv[0..512), V2 = kv[512..1024).
// O = Qp + A*V2 is written IN PLACE over QpO (each element read once by its
// owner lane strictly before the write -> no hazard).
DEVI void att_m1(u16* QpO, const float* __restrict__ wkT, const float* __restrict__ bk,
                 const float* __restrict__ wvT, const float* __restrict__ bv,
                 float* kv, const float* HT, float* sS, int tid) {
    if (tid < 256) {   // K2 = H@wk+bk (tid<128), V2 = H@wv+bv (tid>=128)
        int n = tid & 127, half = tid >> 7;
        const float* wp = (half ? wvT : wkT) + n * 128;
        const float* bsel = half ? bv : bk;
        f32x4 acc = {0.f, 0.f, 0.f, 0.f};
        #pragma unroll 4
        for (int j4 = 0; j4 < 32; ++j4) {
            f32x4 w4 = *(const f32x4*)(wp + j4 * 4);
            #pragma unroll
            for (int j = 0; j < 4; ++j) {
                f32x4 h4 = *(const f32x4*)(HT + (j4 * 4 + j) * 4);
                acc[0] += h4[0] * w4[j]; acc[1] += h4[1] * w4[j];
                acc[2] += h4[2] * w4[j]; acc[3] += h4[3] * w4[j];
            }
        }
        float bb = bsel[n];
        float* dst = kv + half * 512;
        dst[0 * 128 + n] = acc[0] + bb; dst[1 * 128 + n] = acc[1] + bb;
        dst[2 * 128 + n] = acc[2] + bb; dst[3 * 128 + n] = acc[3] + bb;
    }
    __syncthreads();
    if (tid < 256) {   // scores + softmax over k=4, per (h,q) in-thread
        int h = tid >> 6, q = tid & 63;
        const float* kb = kv + h * 32;   // K2
        f32x4 s = {0.f, 0.f, 0.f, 0.f};
        #pragma unroll
        for (int d8 = 0; d8 < 4; ++d8) {
            short8 q8 = *(const short8*)(QpO + swz(q, h * 32 + d8 * 8));
            f32x4 kra[4], krb[4];
            #pragma unroll
            for (int c = 0; c < 4; ++c) {
                kra[c] = *(const f32x4*)(kb + c * 128 + d8 * 8);
                krb[c] = *(const f32x4*)(kb + c * 128 + d8 * 8 + 4);
            }
            #pragma unroll
            for (int j = 0; j < 4; ++j) {
                float qv = b2f((u16)q8[j]);
                s[0] += qv * kra[0][j]; s[1] += qv * kra[1][j];
                s[2] += qv * kra[2][j]; s[3] += qv * kra[3][j];
            }
            #pragma unroll
            for (int j = 0; j < 4; ++j) {
                float qv = b2f((u16)q8[4 + j]);
                s[0] += qv * krb[0][j]; s[1] += qv * krb[1][j];
                s[2] += qv * krb[2][j]; s[3] += qv * krb[3][j];
            }
        }
        float s0 = s[0] * SCALE, s1 = s[1] * SCALE, s2 = s[2] * SCALE, s3 = s[3] * SCALE;
        float m = fmaxf(fmaxf(s0, s1), fmaxf(s2, s3));
        s0 = __expf(s0 - m); s1 = __expf(s1 - m); s2 = __expf(s2 - m); s3 = __expf(s3 - m);
        float inv = 1.f / (s0 + s1 + s2 + s3);
        f32x4 a; a[0] = s0 * inv; a[1] = s1 * inv; a[2] = s2 * inv; a[3] = s3 * inv;
        *(f32x4*)(sS + (h * 64 + q) * 4) = a;
    }
    __syncthreads();
    #pragma unroll
    for (int ii = 0; ii < 16; ++ii) {   // O = Qp + A*V2, in place
        int idx = tid + ii * 512;
        int q = idx >> 7, n = idx & 127, h = n >> 5;
        f32x4 a4 = *(const f32x4*)(sS + (h * 64 + q) * 4);
        int e = swz(q, n);
        float o = b2f(QpO[e]);
        o += a4[0] * kv[512 + 0 * 128 + n] + a4[1] * kv[512 + 1 * 128 + n]
           + a4[2] * kv[512 + 2 * 128 + n] + a4[3] * kv[512 + 3 * 128 + n];
        QpO[e] = f2b(o);
    }
    __syncthreads();
}

__global__ __launch_bounds__(512, 4) void fused_kernel(Params P) {
    __shared__ __align__(16) u16 R0[128 * PT];   // 16 KB  (K^T tile / f32 scr overlay)
    __shared__ __align__(16) u16 R1[64 * 128];   // 16 KB  (swizzled A-tile / f32 overlay)
    __shared__ __align__(16) u16 R2[64 * 128];   // 16 KB  (swizzled A-tile)
    __shared__ __align__(16) float sS[1024];     // 4 KB   -> 52 KB total, 3 blocks/CU
    float* R0f = (float*)R0;
    float* R1f = (float*)R1;

    const int b = blockIdx.x;
    const int tid = threadIdx.x;
    const int l = tid & 63, w = tid >> 6;
    const int lr = l & 15, lq = l >> 4;
    const int Mt = w & 3, Ntb = (w >> 2) * 4;

    const float* v_in = P.in[0] + b * (64 * 256);
    const float* W_in = P.in[1] + b * (64 * 64);
    const float* Q_in = P.in[2] + b * 256;
    const float* ft = P.ft;

    f32x4 z = {0.f, 0.f, 0.f, 0.f};

    // ---- Phase 1: RankAdd (Vh = v + W@pe_w + pe_b) staged into R1 (cols 0..127)
    //      and R2 (cols 128..255), then three K=256 GEMMs as sequential passes. ----
    {
        const float* wrow = W_in + (Mt * 16 + lr) * 64 + lq * 8;
        #pragma unroll 1
        for (int p = 0; p < 2; ++p) {
            f32x4 ar[4];
            #pragma unroll
            for (int i = 0; i < 4; ++i) ar[i] = z;
            #pragma unroll
            for (int ks = 0; ks < 2; ++ks) {   // W @ pe_w, K=64 (f32 -> bf16 A-frag)
                f32x4 w0 = *(const f32x4*)(wrow + ks * 32);
                f32x4 w1 = *(const f32x4*)(wrow + ks * 32 + 4);
                short8 af;
                #pragma unroll
                for (int j = 0; j < 4; ++j) { af[j] = (short)f2b(w0[j]); af[4 + j] = (short)f2b(w1[j]); }
                #pragma unroll
                for (int i = 0; i < 4; ++i) {
                    int ntg = p * 8 + Ntb + i;
                    short8 bfr = *(const short8*)(P.wrep + RW_PEW + ((ntg * 2 + ks) * 64 + l) * 8);
                    ar[i] = MFMA(af, bfr, ar[i]);
                }
            }
            u16* dst = p ? R2 : R1;
            #pragma unroll
            for (int i = 0; i < 4; ++i) {
                int coll = (Ntb + i) * 16 + lr;
                int colg = p * 128 + coll;
                float pb = P.in[4][colg];   // pe_b
                #pragma unroll
                for (int r = 0; r < 4; ++r) {
                    int row = Mt * 16 + lq * 4 + r;
                    dst[swz(row, coll)] = f2b(ar[i][r] + pb + v_in[row * 256 + colg]);
                }
            }
        }
        __syncthreads();

        // K-pass: Kp = Vh @ wk  -> Kp^T in R0 (unswizzled [128][PT])
        {
            f32x4 aK[4];
            #pragma unroll
            for (int i = 0; i < 4; ++i) aK[i] = z;
            #pragma unroll
            for (int p = 0; p < 2; ++p) {
                const u16* At = p ? R2 : R1;
                #pragma unroll
                for (int ks = 0; ks < 4; ++ks) {
                    short8 af = *(const short8*)(At + swz(Mt * 16 + lr, ks * 32 + lq * 8));
                    int kk = p * 4 + ks;
                    #pragma unroll
                    for (int i = 0; i < 4; ++i) {
                        int nt = Ntb + i;
                        short8 b0 = *(const short8*)(P.wrep + RW_I1M0_WK + ((nt * 8 + kk) * 64 + l) * 8);
                        aK[i] = MFMA(af, b0, aK[i]);
                    }
                }
            }
            #pragma unroll
            for (int i = 0; i < 4; ++i) {
                int col = (Ntb + i) * 16 + lr;
                float bkv = P.in[9][col];    // i1_m0_bk
                #pragma unroll
                for (int r = 0; r < 4; ++r) {
                    int row = Mt * 16 + lq * 4 + r;
                    R0[col * PT + row] = f2b(aK[i][r] + bkv);
                }
            }
        }
        // Q+V pass: Vp = Vh @ wv, Qp1 = Vh @ i1_m1_wq (held in regs until Vh dead)
        {
            f32x4 aV[4], aQ[4];
            #pragma unroll
            for (int i = 0; i < 4; ++i) { aV[i] = z; aQ[i] = z; }
            #pragma unroll
            for (int p = 0; p < 2; ++p) {
                const u16* At = p ? R2 : R1;
                #pragma unroll
                for (int ks = 0; ks < 4; ++ks) {
                    short8 af = *(const short8*)(At + swz(Mt * 16 + lr, ks * 32 + lq * 8));
                    int kk = p * 4 + ks;
                    #pragma unroll
                    for (int i = 0; i < 4; ++i) {
                        int nt = Ntb + i;
                        short8 b1 = *(const short8*)(P.wrep + RW_I1M0_WV + ((nt * 8 + kk) * 64 + l) * 8);
                        aV[i] = MFMA(af, b1, aV[i]);
                        short8 b2v = *(const short8*)(P.wrep + RW_I1M1_WQ + ((nt * 8 + kk) * 64 + l) * 8);
                        aQ[i] = MFMA(af, b2v, aQ[i]);
                    }
                }
            }
            __syncthreads();   // all Vh reads done; R1/R2 can be overwritten
            #pragma unroll
            for (int i = 0; i < 4; ++i) {
                int col = (Ntb + i) * 16 + lr;
                float bvv = P.in[11][col];   // i1_m0_bv
                float bqv = P.in[15][col];   // i1_m1_bq
                #pragma unroll
                for (int r = 0; r < 4; ++r) {
                    int row = Mt * 16 + lq * 4 + r;
                    R1[swz(row, col)] = f2b(aV[i][r] + bvv);
                    R2[swz(row, col)] = f2b(aQ[i][r] + bqv);
                }
            }
        }
        __syncthreads();
    }

    // ---- ISAB1 ----
    att_m0(P.qpre, ft + FT_I1M0_WO, P.in[13], R0, R1, R0f, sS, tid);       // H1'^T -> R0f+512
    att_m1(R2, ft + FT_I1M1_WK, P.in[17], ft + FT_I1M1_WV, P.in[19],
           R1f, R0f + 512, sS, tid);                                       // O2 in place (R2)
    gemm128<2>(R2, P.wrep + RW_I1M1_WO, P.in[21], R1, tid);                // X -> R1
    __syncthreads();
    // ---- ISAB2 ----
    gemm128<1>(R1, P.wrep + RW_I2M0_WK, P.in[26], R0, tid);                // Kp3^T -> R0
    gemm128<0>(R1, P.wrep + RW_I2M0_WV, P.in[28], R2, tid);                // Vp3 -> R2
    __syncthreads();
    att_m0(P.qpre + 512, ft + FT_I2M0_WO, P.in[30], R0, R2, R0f, sS, tid); // H2'^T -> R0f+512
    gemm128<0>(R1, P.wrep + RW_I2M1_WQ, P.in[32], R2, tid);                // Qp3 -> R2
    __syncthreads();
    att_m1(R2, ft + FT_I2M1_WK, P.in[34], ft + FT_I2M1_WV, P.in[36],
           R1f, R0f + 512, sS, tid);                                       // O4 in place (R2)
    gemm128<2>(R2, P.wrep + RW_I2M1_WO, P.in[38], R1, tid);                // Xf -> R1
    __syncthreads();
    // ---- decoder MAB ----
    gemm128<1>(R1, P.wrep + RW_DEC_WK, P.in[42], R0, tid);                 // Kpd^T -> R0
    gemm128<0>(R1, P.wrep + RW_DEC_WV, P.in[44], R2, tid);                 // Vpd -> R2
    __syncthreads();
    // R1 (Xf) is dead from here: R1f is the decoder f32 scratch.
    // R1f[0..128) = Qd, R1f[128..256) = O5, R1f[256..384) = o

    {   // Qp_dec partials: [1,256]@[256,128], k split in 4, transposed f32 weights
        int n = tid & 127, c = tid >> 7;
        const float* wp = ft + FT_DEC_WQ + n * 256 + c * 64;
        const float* qq = Q_in + c * 64;
        float acc = 0.f;
        #pragma unroll 8
        for (int k4 = 0; k4 < 16; ++k4) {
            f32x4 w4 = *(const f32x4*)(wp + k4 * 4);
            f32x4 q4 = *(const f32x4*)(qq + k4 * 4);
            acc += q4[0] * w4[0] + q4[1] * w4[1] + q4[2] * w4[2] + q4[3] * w4[3];
        }
        sS[c * 128 + n] = acc;
    }
    __syncthreads();
    if (tid < 128) {   // Qd -> R1f[0..128)
        R1f[tid] = sS[tid] + sS[128 + tid] + sS[256 + tid] + sS[384 + tid] + P.in[40][tid];
    }
    __syncthreads();
    if (tid < 256) {   // scores s[h][k]
        int h = tid >> 6, k = tid & 63;
        const float* qd = R1f + h * 32;
        const u16* kp = R0 + (h * 32) * PT + k;
        float s = 0.f;
        #pragma unroll
        for (int d8 = 0; d8 < 8; ++d8) {
            f32x4 q4 = *(const f32x4*)(qd + d8 * 4);
            #pragma unroll
            for (int j = 0; j < 4; ++j) s += q4[j] * b2f(kp[(d8 * 4 + j) * PT]);
        }
        sS[h * 64 + k] = s * SCALE;
    }
    __syncthreads();
    if (w < 4) {   // softmax, wave h over 64 k
        float v = sS[w * 64 + l];
        float m = v;
        #pragma unroll
        for (int off = 1; off < 64; off <<= 1) m = fmaxf(m, __shfl_xor(m, off));
        v = __expf(v - m);
        float su = v;
        #pragma unroll
        for (int off = 1; off < 64; off <<= 1) su += __shfl_xor(su, off);
        sS[w * 64 + l] = v / su;
    }
    __syncthreads();
    if (tid < 128) {   // O5 = Qd + A*Vpd -> R1f[128..256)
        int n = tid, h = n >> 5;
        float o = R1f[n];
        const float* arr = sS + h * 64;
        #pragma unroll 8
        for (int k8 = 0; k8 < 16; ++k8) {
            f32x4 a4 = *(const f32x4*)(arr + k8 * 4);
            #pragma unroll
            for (int j = 0; j < 4; ++j) o += a4[j] * b2f(R2[swz(k8 * 4 + j, n)]);
        }
        R1f[128 + n] = o;
    }
    __syncthreads();
    if (tid < 256) {   // O5@dec_wo partials (k split 2) -> sS[256..512)
        int n = tid & 127, c = tid >> 7;
        const float* wp = ft + FT_DEC_WO + n * 128 + c * 64;
        const float* ov = R1f + 128 + c * 64;
        float acc = 0.f;
        #pragma unroll 8
        for (int k4 = 0; k4 < 16; ++k4) {
            f32x4 w4 = *(const f32x4*)(wp + k4 * 4);
            f32x4 o4 = *(const f32x4*)(ov + k4 * 4);
            acc += o4[0] * w4[0] + o4[1] * w4[1] + o4[2] * w4[2] + o4[3] * w4[3];
        }
        sS[256 + c * 128 + n] = acc;
    }
    __syncthreads();
    if (tid < 128) {   // o = O5 + relu(... + bo) -> R1f[256..384)
        float val = sS[256 + tid] + sS[384 + tid] + P.in[46][tid];
        R1f[256 + tid] = R1f[128 + tid] + fmaxf(val, 0.f);
    }
    __syncthreads();
    {   // out = o @ out_w + out_b, k split 2, transposed f32 weights
        int j = tid & 255, c = tid >> 8;
        const float* wp = ft + FT_OUT_W + j * 128 + c * 64;
        const float* ov = R1f + 256 + c * 64;
        float acc = 0.f;
        #pragma unroll 8
        for (int k4 = 0; k4 < 16; ++k4) {
            f32x4 w4 = *(const f32x4*)(wp + k4 * 4);
            f32x4 o4 = *(const f32x4*)(ov + k4 * 4);
            acc += o4[0] * w4[0] + o4[1] * w4[1] + o4[2] * w4[2] + o4[3] * w4[3];
        }
        sS[c * 256 + j] = acc;
    }
    __syncthreads();
    if (tid < 256) {
        P.out[b * 256 + tid] = sS[tid] + sS[256 + tid] + P.in[48][tid];
    }
}

extern "C" void kernel_launch(void* const* d_in, const int* in_sizes, int n_in,
                              void* d_out, int out_size, void* d_ws, size_t ws_size,
                              hipStream_t stream) {
    RepArgs ra;
    const int srcidx[11] = {3, 8, 10, 14, 20, 25, 27, 31, 37, 41, 43};
    for (int i = 0; i < 11; ++i) ra.src[i] = (const float*)d_in[srcidx[i]];
    const int tidx[9] = {12, 29, 16, 18, 33, 35, 45, 39, 47};
    for (int i = 0; i < 9; ++i) ra.tsrc[i] = (const float*)d_in[tidx[i]];
    ra.dst = (u16*)d_ws;
    ra.fdst = (float*)((char*)d_ws + RW_END * 2);
    ra.qpre = ra.fdst + FT_END;
    ra.I1 = (const float*)d_in[5];  ra.wq1 = (const float*)d_in[6];  ra.bq1 = (const float*)d_in[7];
    ra.I2 = (const float*)d_in[22]; ra.wq2 = (const float*)d_in[23]; ra.bq2 = (const float*)d_in[24];
    repack_kernel<<<204, 256, 0, stream>>>(ra);

    Params P;
    for (int i = 0; i < 49; ++i) P.in[i] = (const float*)d_in[i];
    P.wrep = (const u16*)d_ws;
    P.ft = (const float*)((char*)d_ws + RW_END * 2);
    P.qpre = P.ft + FT_END;
    P.out = (float*)d_out;
    fused_kernel<<<4096, 512, 0, stream>>>(P);
}

// Round 5
// 1372.358 us; speedup vs baseline: 1.1317x; 1.1317x over previous
//
#include <hip/hip_runtime.h>
#include <hip/hip_bf16.h>

typedef unsigned short u16;
typedef unsigned int u32;
typedef __attribute__((ext_vector_type(8))) short short8;
typedef __attribute__((ext_vector_type(4))) float f32x4;

#define DEVI static __device__ __forceinline__

DEVI u16 f2b(float f) {
    union { float f; unsigned v; } x; x.f = f;
    unsigned r = x.v + 0x7fffu + ((x.v >> 16) & 1u);
    return (u16)(r >> 16);
}
DEVI float b2f(u16 u) { union { unsigned v; float f; } x; x.v = ((unsigned)u) << 16; return x.f; }

#define MFMA(a, b, c) __builtin_amdgcn_mfma_f32_16x16x32_bf16((a), (b), (c), 0, 0, 0)

// XOR-swizzle for [64][128] bf16 A-tiles: permute 16B granules within a row
// by row&7 so column-strided b128 reads spread over all 32 banks.
DEVI int swz(int row, int col) {
    return row * 128 + ((((col >> 3) ^ (row & 7))) << 3) + (col & 7);
}

// ws layout:
//   [0 .. RW_END) bf16 elems           : repacked MFMA B-fragment weights
//   then f32 region (FT_* float offs)  : transposed f32 weights for VALU phases
//   then qpre f32 [2][4][128]
#define RW_PEW     0
#define RW_I1M0_WK 16384
#define RW_I1M0_WV 49152
#define RW_I1M1_WQ 81920
#define RW_I1M1_WO 114688
#define RW_I2M0_WK 131072
#define RW_I2M0_WV 147456
#define RW_I2M1_WQ 163840
#define RW_I2M1_WO 180224
#define RW_DEC_WK  196608
#define RW_DEC_WV  212992
#define RW_END     229376   // bf16 elems

// f32 transposed weights, offsets in floats from ft base
#define FT_I1M0_WO 0
#define FT_I2M0_WO 16384
#define FT_I1M1_WK 32768
#define FT_I1M1_WV 49152
#define FT_I2M1_WK 65536
#define FT_I2M1_WV 81920
#define FT_DEC_WO  98304
#define FT_DEC_WQ  114688
#define FT_OUT_W   147456
#define FT_END     180224

#define PA 128   // logical pitch of [64][128] tiles (swizzled addressing via swz())
#define PT 66    // pitch of transposed-K buffers [128][66]: col stride 66*2B ≡ 33 dwords
                 // -> bank advances by 1 per col, breaking the 16-way write conflict at PT=64
#define SCALE 0.08838834764831845f  // 1/sqrt(128)

struct Params {
    const float* in[49];   // ALL reference inputs are float32
    const u16* wrep;       // repacked bf16 weight fragments
    const float* ft;       // transposed f32 weights
    const float* qpre;     // [2][4][128] fp32 (precomputed I@wq+bq for i1m0 / i2m0)
    float* out;            // float32 output
};

struct RepArgs {
    const float* src[11];
    const float* tsrc[9];
    u16* dst;
    float* fdst;
    float* qpre;
    const float* I1; const float* wq1; const float* bq1;
    const float* I2; const float* wq2; const float* bq2;
};

// Repack f32 weights [K][N] row-major -> bf16 MFMA B fragments (t < 28672),
// transposed f32 copies wT[n*K+k] = w[k*N+n] (28672 <= t < 51200),
// batch-independent Qp for the two ISAB m0 blocks (t >= 51200).
__global__ void repack_kernel(RepArgs a) {
    const int offs[11] = {RW_PEW, RW_I1M0_WK, RW_I1M0_WV, RW_I1M1_WQ, RW_I1M1_WO,
                          RW_I2M0_WK, RW_I2M0_WV, RW_I2M1_WQ, RW_I2M1_WO, RW_DEC_WK, RW_DEC_WV};
    const int Ks[11] = {64, 256, 256, 256, 128, 128, 128, 128, 128, 128, 128};
    const int Ns[11] = {256, 128, 128, 128, 128, 128, 128, 128, 128, 128, 128};
    int t = blockIdx.x * 256 + threadIdx.x;
    if (t < 28672) {
        int m = 0, u = t;
        for (m = 0; m < 11; ++m) {
            int un = (Ks[m] * Ns[m]) >> 3;
            if (u < un) break;
            u -= un;
        }
        int l = u & 63, f = u >> 6;
        int ksteps = Ks[m] >> 5;
        int nt = f / ksteps, ks = f - nt * ksteps;
        int N = Ns[m];
        const float* s = a.src[m] + (ks * 32 + (l >> 4) * 8) * N + nt * 16 + (l & 15);
        u16* d = a.dst + offs[m] + ((f * 64 + l) << 3);
        short8 v;
        #pragma unroll
        for (int j = 0; j < 8; ++j) v[j] = (short)f2b(s[j * N]);
        *(short8*)d = v;
    } else if (t < 51200) {
        // transposed f32 repack: each thread writes 8 contiguous k at one n
        const int TK[9] = {128, 128, 128, 128, 128, 128, 128, 256, 128};
        const int TN[9] = {128, 128, 128, 128, 128, 128, 128, 128, 256};
        const int TOFF[9] = {FT_I1M0_WO, FT_I2M0_WO, FT_I1M1_WK, FT_I1M1_WV,
                             FT_I2M1_WK, FT_I2M1_WV, FT_DEC_WO, FT_DEC_WQ, FT_OUT_W};
        int u = t - 28672;
        int m = 0;
        for (m = 0; m < 9; ++m) {
            int un = (TK[m] * TN[m]) >> 3;
            if (u < un) break;
            u -= un;
        }
        int K = TK[m], N = TN[m];
        int kc = K >> 3;
        int n = u / kc, k0 = (u - n * kc) << 3;
        const float* s = a.tsrc[m] + k0 * N + n;
        float* d = a.fdst + TOFF[m] + n * K + k0;
        f32x4 v0, v1;
        #pragma unroll
        for (int j = 0; j < 4; ++j) v0[j] = s[j * N];
        #pragma unroll
        for (int j = 0; j < 4; ++j) v1[j] = s[(4 + j) * N];
        *(f32x4*)d = v0;
        *(f32x4*)(d + 4) = v1;
    } else {
        int q_t = t - 51200;             // 0..1023
        int which = q_t >> 9, q = (q_t >> 7) & 3, n = q_t & 127;
        const float* I  = which ? a.I2  : a.I1;
        const float* wq = which ? a.wq2 : a.wq1;
        const float* bq = which ? a.bq2 : a.bq1;
        float acc = bq[n];
        for (int k = 0; k < 128; ++k) acc += I[q * 128 + k] * wq[k * 128 + n];
        a.qpre[q_t] = acc;
    }
}

// [64,128] = A(lds, swizzled [64][128] bf16) @ Brep(K=128, repacked bf16) + bias(f32)
// MODE 0: out swizzled [64][128]   MODE 1: transposed out[col*PT+row] (unswizzled)
// MODE 2: out = A + relu(D+bias)  (residual = A), out swizzled
template <int MODE>
DEVI void gemm128(const u16* A, const u16* __restrict__ Brep,
                  const float* __restrict__ bias, u16* out, int tid) {
    int l = tid & 63, w = tid >> 6;
    int lr = l & 15, lq = l >> 4;
    int Mt = w & 3, Ntb = (w >> 2) * 4;
    f32x4 z = {0.f, 0.f, 0.f, 0.f};
    f32x4 acc[4];
    #pragma unroll
    for (int i = 0; i < 4; ++i) acc[i] = z;
    int arow = Mt * 16 + lr;
    #pragma unroll
    for (int ks = 0; ks < 4; ++ks) {
        short8 af = *(const short8*)(A + swz(arow, ks * 32 + lq * 8));
        #pragma unroll
        for (int i = 0; i < 4; ++i) {
            int nt = Ntb + i;
            short8 bfr = *(const short8*)(Brep + (((nt << 2) + ks) * 64 + l) * 8);
            acc[i] = MFMA(af, bfr, acc[i]);
        }
    }
    #pragma unroll
    for (int i = 0; i < 4; ++i) {
        int col = (Ntb + i) * 16 + lr;
        float bv = bias[col];
        #pragma unroll
        for (int r = 0; r < 4; ++r) {
            int row = Mt * 16 + lq * 4 + r;
            float v = acc[i][r] + bv;
            if (MODE == 2) v = b2f(A[swz(row, col)]) + fmaxf(v, 0.f);
            if (MODE == 1) out[col * PT + row] = f2b(v);
            else           out[swz(row, col)] = f2b(v);
        }
    }
}

// ISAB m0 attention: Sq=4 (qpre fp32), Sk=64. KT=[128][PT] bf16 (unswizzled),
// V = swizzled [64][128] bf16.
// scr aliases KT's storage as float (KT dead after the score phase):
//   scr[0..512)   = O^T  [n][q]
//   scr[512..1024)= H'^T [n][q]   (survives until att_m1's K2/V2 phase)
DEVI void att_m0(const float* __restrict__ qpre, const float* __restrict__ woT,
                 const float* __restrict__ bo, const u16* KT, const u16* V,
                 float* scr, float* sS, int tid) {
    #pragma unroll
    for (int ii = 0; ii < 2; ++ii) {         // 1024 scores: s[h][q][k]
        int idx = tid + ii * 512;
        int h = idx >> 8, q = (idx >> 6) & 3, k = idx & 63;
        const float* qp = qpre + q * 128 + h * 32;
        const u16* kp = KT + (h * 32) * PT + k;
        float s = 0.f;
        #pragma unroll
        for (int d8 = 0; d8 < 8; ++d8) {
            f32x4 q4 = *(const f32x4*)(qp + d8 * 4);
            #pragma unroll
            for (int j = 0; j < 4; ++j) s += q4[j] * b2f(kp[(d8 * 4 + j) * PT]);
        }
        sS[(h * 4 + q) * 64 + k] = s * SCALE;
    }
    __syncthreads();
    {   // softmax over k=64 for 16 rows
        int w = tid >> 6, l = tid & 63;
        int row = w * 2 + (l >> 5);
        int j = (l & 31) * 2;
        float e0 = sS[row * 64 + j], e1 = sS[row * 64 + j + 1];
        float m = fmaxf(e0, e1);
        #pragma unroll
        for (int off = 1; off < 32; off <<= 1) m = fmaxf(m, __shfl_xor(m, off));
        e0 = __expf(e0 - m); e1 = __expf(e1 - m);
        float su = e0 + e1;
        #pragma unroll
        for (int off = 1; off < 32; off <<= 1) su += __shfl_xor(su, off);
        float inv = 1.f / su;
        sS[row * 64 + j] = e0 * inv;
        sS[row * 64 + j + 1] = e1 * inv;
    }
    __syncthreads();
    {   // O^T = qpre + A*V  -> scr[n*4+q]  (KT dead now; conflict-free writes)
        int q = tid & 3, n = tid >> 2, h = n >> 5;
        float o = qpre[q * 128 + n];
        const float* ar = sS + (h * 4 + q) * 64;
        #pragma unroll 8
        for (int k8 = 0; k8 < 16; ++k8) {
            f32x4 a4 = *(const f32x4*)(ar + k8 * 4);
            #pragma unroll
            for (int j = 0; j < 4; ++j) o += a4[j] * b2f(V[swz(k8 * 4 + j, n)]);
        }
        scr[n * 4 + q] = o;
    }
    __syncthreads();
    if (tid < 256) {   // O@wo partials (k split 2), transposed f32 weights
        int n = tid & 127, c = tid >> 7;
        const float* wp = woT + n * 128 + c * 64;
        f32x4 acc = {0.f, 0.f, 0.f, 0.f};
        #pragma unroll 4
        for (int k4 = 0; k4 < 16; ++k4) {
            f32x4 w4 = *(const f32x4*)(wp + k4 * 4);
            #pragma unroll
            for (int j = 0; j < 4; ++j) {
                f32x4 o4 = *(const f32x4*)(scr + (c * 64 + k4 * 4 + j) * 4);
                acc[0] += o4[0] * w4[j]; acc[1] += o4[1] * w4[j];
                acc[2] += o4[2] * w4[j]; acc[3] += o4[3] * w4[j];
            }
        }
        *(f32x4*)(sS + c * 512 + n * 4) = acc;
    }
    __syncthreads();
    {   // H'^T = O + relu(O@wo + bo) -> scr[512 + n*4 + q]
        int q = tid & 3, n = tid >> 2;
        float val = sS[n * 4 + q] + sS[512 + n * 4 + q] + bo[n];
        scr[512 + n * 4 + q] = scr[n * 4 + q] + fmaxf(val, 0.f);
    }
    __syncthreads();
}

// ISAB m1 attention: Sq=64 (QpO = swizzled Qp tile, bf16), Sk=4.
// HT = H'^T [128][4] f32 (R0f+512). kv = raw f32 scratch (overlay on a dead tile):
// K2 = kv[0..512), V2 = kv[512..1024).
// O = Qp + A*V2 is written IN PLACE over QpO (each element read once by its
// owner lane strictly before the write -> no hazard).
DEVI void att_m1(u16* QpO, const float* __restrict__ wkT, const float* __restrict__ bk,
                 const float* __restrict__ wvT, const float* __restrict__ bv,
                 float* kv, const float* HT, float* sS, int tid) {
    if (tid < 256) {   // K2 = H@wk+bk (tid<128), V2 = H@wv+bv (tid>=128)
        int n = tid & 127, half = tid >> 7;
        const float* wp = (half ? wvT : wkT) + n * 128;
        const float* bsel = half ? bv : bk;
        f32x4 acc = {0.f, 0.f, 0.f, 0.f};
        #pragma unroll 4
        for (int j4 = 0; j4 < 32; ++j4) {
            f32x4 w4 = *(const f32x4*)(wp + j4 * 4);
            #pragma unroll
            for (int j = 0; j < 4; ++j) {
                f32x4 h4 = *(const f32x4*)(HT + (j4 * 4 + j) * 4);
                acc[0] += h4[0] * w4[j]; acc[1] += h4[1] * w4[j];
                acc[2] += h4[2] * w4[j]; acc[3] += h4[3] * w4[j];
            }
        }
        float bb = bsel[n];
        float* dst = kv + half * 512;
        dst[0 * 128 + n] = acc[0] + bb; dst[1 * 128 + n] = acc[1] + bb;
        dst[2 * 128 + n] = acc[2] + bb; dst[3 * 128 + n] = acc[3] + bb;
    }
    __syncthreads();
    if (tid < 256) {   // scores + softmax over k=4, per (h,q) in-thread
        int h = tid >> 6, q = tid & 63;
        const float* kb = kv + h * 32;   // K2
        f32x4 s = {0.f, 0.f, 0.f, 0.f};
        #pragma unroll
        for (int d8 = 0; d8 < 4; ++d8) {
            short8 q8 = *(const short8*)(QpO + swz(q, h * 32 + d8 * 8));
            f32x4 kra[4], krb[4];
            #pragma unroll
            for (int c = 0; c < 4; ++c) {
                kra[c] = *(const f32x4*)(kb + c * 128 + d8 * 8);
                krb[c] = *(const f32x4*)(kb + c * 128 + d8 * 8 + 4);
            }
            #pragma unroll
            for (int j = 0; j < 4; ++j) {
                float qv = b2f((u16)q8[j]);
                s[0] += qv * kra[0][j]; s[1] += qv * kra[1][j];
                s[2] += qv * kra[2][j]; s[3] += qv * kra[3][j];
            }
            #pragma unroll
            for (int j = 0; j < 4; ++j) {
                float qv = b2f((u16)q8[4 + j]);
                s[0] += qv * krb[0][j]; s[1] += qv * krb[1][j];
                s[2] += qv * krb[2][j]; s[3] += qv * krb[3][j];
            }
        }
        float s0 = s[0] * SCALE, s1 = s[1] * SCALE, s2 = s[2] * SCALE, s3 = s[3] * SCALE;
        float m = fmaxf(fmaxf(s0, s1), fmaxf(s2, s3));
        s0 = __expf(s0 - m); s1 = __expf(s1 - m); s2 = __expf(s2 - m); s3 = __expf(s3 - m);
        float inv = 1.f / (s0 + s1 + s2 + s3);
        f32x4 a; a[0] = s0 * inv; a[1] = s1 * inv; a[2] = s2 * inv; a[3] = s3 * inv;
        *(f32x4*)(sS + (h * 64 + q) * 4) = a;
    }
    __syncthreads();
    #pragma unroll
    for (int ii = 0; ii < 16; ++ii) {   // O = Qp + A*V2, in place
        int idx = tid + ii * 512;
        int q = idx >> 7, n = idx & 127, h = n >> 5;
        f32x4 a4 = *(const f32x4*)(sS + (h * 64 + q) * 4);
        int e = swz(q, n);
        float o = b2f(QpO[e]);
        o += a4[0] * kv[512 + 0 * 128 + n] + a4[1] * kv[512 + 1 * 128 + n]
           + a4[2] * kv[512 + 2 * 128 + n] + a4[3] * kv[512 + 3 * 128 + n];
        QpO[e] = f2b(o);
    }
    __syncthreads();
}

__global__ __launch_bounds__(512, 2) void fused_kernel(Params P) {
    __shared__ __align__(16) u16 R0[128 * PT];   // 16.5 KB (K^T tile / f32 scr overlay)
    __shared__ __align__(16) u16 R1[64 * 128];   // 16 KB  (swizzled A-tile / f32 overlay)
    __shared__ __align__(16) u16 R2[64 * 128];   // 16 KB  (swizzled A-tile)
    __shared__ __align__(16) float sS[1024];     // 4 KB   -> 52.5 KB total
    float* R0f = (float*)R0;
    float* R1f = (float*)R1;

    const int b = blockIdx.x;
    const int tid = threadIdx.x;
    const int l = tid & 63, w = tid >> 6;
    const int lr = l & 15, lq = l >> 4;
    const int Mt = w & 3, Ntb = (w >> 2) * 4;

    const float* v_in = P.in[0] + b * (64 * 256);
    const float* W_in = P.in[1] + b * (64 * 64);
    const float* Q_in = P.in[2] + b * 256;
    const float* ft = P.ft;

    f32x4 z = {0.f, 0.f, 0.f, 0.f};

    // ---- Phase 1: RankAdd (Vh = v + W@pe_w + pe_b) staged into R1 (cols 0..127)
    //      and R2 (cols 128..255), then three K=256 GEMMs as sequential passes. ----
    {
        const float* wrow = W_in + (Mt * 16 + lr) * 64 + lq * 8;
        #pragma unroll 1
        for (int p = 0; p < 2; ++p) {
            f32x4 ar[4];
            #pragma unroll
            for (int i = 0; i < 4; ++i) ar[i] = z;
            #pragma unroll
            for (int ks = 0; ks < 2; ++ks) {   // W @ pe_w, K=64 (f32 -> bf16 A-frag)
                f32x4 w0 = *(const f32x4*)(wrow + ks * 32);
                f32x4 w1 = *(const f32x4*)(wrow + ks * 32 + 4);
                short8 af;
                #pragma unroll
                for (int j = 0; j < 4; ++j) { af[j] = (short)f2b(w0[j]); af[4 + j] = (short)f2b(w1[j]); }
                #pragma unroll
                for (int i = 0; i < 4; ++i) {
                    int ntg = p * 8 + Ntb + i;
                    short8 bfr = *(const short8*)(P.wrep + RW_PEW + ((ntg * 2 + ks) * 64 + l) * 8);
                    ar[i] = MFMA(af, bfr, ar[i]);
                }
            }
            u16* dst = p ? R2 : R1;
            #pragma unroll
            for (int i = 0; i < 4; ++i) {
                int coll = (Ntb + i) * 16 + lr;
                int colg = p * 128 + coll;
                float pb = P.in[4][colg];   // pe_b
                #pragma unroll
                for (int r = 0; r < 4; ++r) {
                    int row = Mt * 16 + lq * 4 + r;
                    dst[swz(row, coll)] = f2b(ar[i][r] + pb + v_in[row * 256 + colg]);
                }
            }
        }
        __syncthreads();

        // K-pass: Kp = Vh @ wk  -> Kp^T in R0 (unswizzled [128][PT])
        {
            f32x4 aK[4];
            #pragma unroll
            for (int i = 0; i < 4; ++i) aK[i] = z;
            #pragma unroll
            for (int p = 0; p < 2; ++p) {
                const u16* At = p ? R2 : R1;
                #pragma unroll
                for (int ks = 0; ks < 4; ++ks) {
                    short8 af = *(const short8*)(At + swz(Mt * 16 + lr, ks * 32 + lq * 8));
                    int kk = p * 4 + ks;
                    #pragma unroll
                    for (int i = 0; i < 4; ++i) {
                        int nt = Ntb + i;
                        short8 b0 = *(const short8*)(P.wrep + RW_I1M0_WK + ((nt * 8 + kk) * 64 + l) * 8);
                        aK[i] = MFMA(af, b0, aK[i]);
                    }
                }
            }
            #pragma unroll
            for (int i = 0; i < 4; ++i) {
                int col = (Ntb + i) * 16 + lr;
                float bkv = P.in[9][col];    // i1_m0_bk
                #pragma unroll
                for (int r = 0; r < 4; ++r) {
                    int row = Mt * 16 + lq * 4 + r;
                    R0[col * PT + row] = f2b(aK[i][r] + bkv);
                }
            }
        }
        // Q+V pass: Vp = Vh @ wv, Qp1 = Vh @ i1_m1_wq (held in regs until Vh dead)
        {
            f32x4 aV[4], aQ[4];
            #pragma unroll
            for (int i = 0; i < 4; ++i) { aV[i] = z; aQ[i] = z; }
            #pragma unroll
            for (int p = 0; p < 2; ++p) {
                const u16* At = p ? R2 : R1;
                #pragma unroll
                for (int ks = 0; ks < 4; ++ks) {
                    short8 af = *(const short8*)(At + swz(Mt * 16 + lr, ks * 32 + lq * 8));
                    int kk = p * 4 + ks;
                    #pragma unroll
                    for (int i = 0; i < 4; ++i) {
                        int nt = Ntb + i;
                        short8 b1 = *(const short8*)(P.wrep + RW_I1M0_WV + ((nt * 8 + kk) * 64 + l) * 8);
                        aV[i] = MFMA(af, b1, aV[i]);
                        short8 b2v = *(const short8*)(P.wrep + RW_I1M1_WQ + ((nt * 8 + kk) * 64 + l) * 8);
                        aQ[i] = MFMA(af, b2v, aQ[i]);
                    }
                }
            }
            __syncthreads();   // all Vh reads done; R1/R2 can be overwritten
            #pragma unroll
            for (int i = 0; i < 4; ++i) {
                int col = (Ntb + i) * 16 + lr;
                float bvv = P.in[11][col];   // i1_m0_bv
                float bqv = P.in[15][col];   // i1_m1_bq
                #pragma unroll
                for (int r = 0; r < 4; ++r) {
                    int row = Mt * 16 + lq * 4 + r;
                    R1[swz(row, col)] = f2b(aV[i][r] + bvv);
                    R2[swz(row, col)] = f2b(aQ[i][r] + bqv);
                }
            }
        }
        __syncthreads();
    }

    // ---- ISAB1 ----
    att_m0(P.qpre, ft + FT_I1M0_WO, P.in[13], R0, R1, R0f, sS, tid);       // H1'^T -> R0f+512
    att_m1(R2, ft + FT_I1M1_WK, P.in[17], ft + FT_I1M1_WV, P.in[19],
           R1f, R0f + 512, sS, tid);                                       // O2 in place (R2)
    gemm128<2>(R2, P.wrep + RW_I1M1_WO, P.in[21], R1, tid);                // X -> R1
    __syncthreads();
    // ---- ISAB2 ----
    gemm128<1>(R1, P.wrep + RW_I2M0_WK, P.in[26], R0, tid);                // Kp3^T -> R0
    gemm128<0>(R1, P.wrep + RW_I2M0_WV, P.in[28], R2, tid);                // Vp3 -> R2
    __syncthreads();
    att_m0(P.qpre + 512, ft + FT_I2M0_WO, P.in[30], R0, R2, R0f, sS, tid); // H2'^T -> R0f+512
    gemm128<0>(R1, P.wrep + RW_I2M1_WQ, P.in[32], R2, tid);                // Qp3 -> R2
    __syncthreads();
    att_m1(R2, ft + FT_I2M1_WK, P.in[34], ft + FT_I2M1_WV, P.in[36],
           R1f, R0f + 512, sS, tid);                                       // O4 in place (R2)
    gemm128<2>(R2, P.wrep + RW_I2M1_WO, P.in[38], R1, tid);                // Xf -> R1
    __syncthreads();
    // ---- decoder MAB ----
    gemm128<1>(R1, P.wrep + RW_DEC_WK, P.in[42], R0, tid);                 // Kpd^T -> R0
    gemm128<0>(R1, P.wrep + RW_DEC_WV, P.in[44], R2, tid);                 // Vpd -> R2
    __syncthreads();
    // R1 (Xf) is dead from here: R1f is the decoder f32 scratch.
    // R1f[0..128) = Qd, R1f[128..256) = O5, R1f[256..384) = o

    {   // Qp_dec partials: [1,256]@[256,128], k split in 4, transposed f32 weights
        int n = tid & 127, c = tid >> 7;
        const float* wp = ft + FT_DEC_WQ + n * 256 + c * 64;
        const float* qq = Q_in + c * 64;
        float acc = 0.f;
        #pragma unroll 8
        for (int k4 = 0; k4 < 16; ++k4) {
            f32x4 w4 = *(const f32x4*)(wp + k4 * 4);
            f32x4 q4 = *(const f32x4*)(qq + k4 * 4);
            acc += q4[0] * w4[0] + q4[1] * w4[1] + q4[2] * w4[2] + q4[3] * w4[3];
        }
        sS[c * 128 + n] = acc;
    }
    __syncthreads();
    if (tid < 128) {   // Qd -> R1f[0..128)
        R1f[tid] = sS[tid] + sS[128 + tid] + sS[256 + tid] + sS[384 + tid] + P.in[40][tid];
    }
    __syncthreads();
    if (tid < 256) {   // scores s[h][k]
        int h = tid >> 6, k = tid & 63;
        const float* qd = R1f + h * 32;
        const u16* kp = R0 + (h * 32) * PT + k;
        float s = 0.f;
        #pragma unroll
        for (int d8 = 0; d8 < 8; ++d8) {
            f32x4 q4 = *(const f32x4*)(qd + d8 * 4);
            #pragma unroll
            for (int j = 0; j < 4; ++j) s += q4[j] * b2f(kp[(d8 * 4 + j) * PT]);
        }
        sS[h * 64 + k] = s * SCALE;
    }
    __syncthreads();
    if (w < 4) {   // softmax, wave h over 64 k
        float v = sS[w * 64 + l];
        float m = v;
        #pragma unroll
        for (int off = 1; off < 64; off <<= 1) m = fmaxf(m, __shfl_xor(m, off));
        v = __expf(v - m);
        float su = v;
        #pragma unroll
        for (int off = 1; off < 64; off <<= 1) su += __shfl_xor(su, off);
        sS[w * 64 + l] = v / su;
    }
    __syncthreads();
    if (tid < 128) {   // O5 = Qd + A*Vpd -> R1f[128..256)
        int n = tid, h = n >> 5;
        float o = R1f[n];
        const float* arr = sS + h * 64;
        #pragma unroll 8
        for (int k8 = 0; k8 < 16; ++k8) {
            f32x4 a4 = *(const f32x4*)(arr + k8 * 4);
            #pragma unroll
            for (int j = 0; j < 4; ++j) o += a4[j] * b2f(R2[swz(k8 * 4 + j, n)]);
        }
        R1f[128 + n] = o;
    }
    __syncthreads();
    if (tid < 256) {   // O5@dec_wo partials (k split 2) -> sS[256..512)
        int n = tid & 127, c = tid >> 7;
        const float* wp = ft + FT_DEC_WO + n * 128 + c * 64;
        const float* ov = R1f + 128 + c * 64;
        float acc = 0.f;
        #pragma unroll 8
        for (int k4 = 0; k4 < 16; ++k4) {
            f32x4 w4 = *(const f32x4*)(wp + k4 * 4);
            f32x4 o4 = *(const f32x4*)(ov + k4 * 4);
            acc += o4[0] * w4[0] + o4[1] * w4[1] + o4[2] * w4[2] + o4[3] * w4[3];
        }
        sS[256 + c * 128 + n] = acc;
    }
    __syncthreads();
    if (tid < 128) {   // o = O5 + relu(... + bo) -> R1f[256..384)
        float val = sS[256 + tid] + sS[384 + tid] + P.in[46][tid];
        R1f[256 + tid] = R1f[128 + tid] + fmaxf(val, 0.f);
    }
    __syncthreads();
    {   // out = o @ out_w + out_b, k split 2, transposed f32 weights
        int j = tid & 255, c = tid >> 8;
        const float* wp = ft + FT_OUT_W + j * 128 + c * 64;
        const float* ov = R1f + 256 + c * 64;
        float acc = 0.f;
        #pragma unroll 8
        for (int k4 = 0; k4 < 16; ++k4) {
            f32x4 w4 = *(const f32x4*)(wp + k4 * 4);
            f32x4 o4 = *(const f32x4*)(ov + k4 * 4);
            acc += o4[0] * w4[0] + o4[1] * w4[1] + o4[2] * w4[2] + o4[3] * w4[3];
        }
        sS[c * 256 + j] = acc;
    }
    __syncthreads();
    if (tid < 256) {
        P.out[b * 256 + tid] = sS[tid] + sS[256 + tid] + P.in[48][tid];
    }
}

extern "C" void kernel_launch(void* const* d_in, const int* in_sizes, int n_in,
                              void* d_out, int out_size, void* d_ws, size_t ws_size,
                              hipStream_t stream) {
    RepArgs ra;
    const int srcidx[11] = {3, 8, 10, 14, 20, 25, 27, 31, 37, 41, 43};
    for (int i = 0; i < 11; ++i) ra.src[i] = (const float*)d_in[srcidx[i]];
    const int tidx[9] = {12, 29, 16, 18, 33, 35, 45, 39, 47};
    for (int i = 0; i < 9; ++i) ra.tsrc[i] = (const float*)d_in[tidx[i]];
    ra.dst = (u16*)d_ws;
    ra.fdst = (float*)((char*)d_ws + RW_END * 2);
    ra.qpre = ra.fdst + FT_END;
    ra.I1 = (const float*)d_in[5];  ra.wq1 = (const float*)d_in[6];  ra.bq1 = (const float*)d_in[7];
    ra.I2 = (const float*)d_in[22]; ra.wq2 = (const float*)d_in[23]; ra.bq2 = (const float*)d_in[24];
    repack_kernel<<<204, 256, 0, stream>>>(ra);

    Params P;
    for (int i = 0; i < 49; ++i) P.in[i] = (const float*)d_in[i];
    P.wrep = (const u16*)d_ws;
    P.ft = (const float*)((char*)d_ws + RW_END * 2);
    P.qpre = P.ft + FT_END;
    P.out = (float*)d_out;
    fused_kernel<<<4096, 512, 0, stream>>>(P);
}